// Round 2
// baseline (500.072 us; speedup 1.0000x reference)
//
#include <hip/hip_runtime.h>
#include <math.h>

#define N_NODES 8192
#define N_COMM 16
#define DIMS 64
#define MROWS 8
#define CBLK 4096

typedef float v4f __attribute__((ext_vector_type(4)));

// ---------------------------------------------------------------------------
// Kernel 1: pi[i,k] = softmax_k( sqrt(d_euc^2 + d_lor^2 + d_sph^2) )
// One lane per (node, k): t = i*16 + k. 16-lane softmax via shfl_xor(1,2,4,8).
// ---------------------------------------------------------------------------
__global__ __launch_bounds__(256) void k_pi(
    const float* __restrict__ node,   // (3, 8192, 64)
    const float* __restrict__ comm,   // (16, 64)
    float* __restrict__ pi)           // (8192, 16)
{
  const int t = blockIdx.x * blockDim.x + threadIdx.x;  // 0..131071
  const int i = t >> 4;
  const int k = t & 15;

  const float* xe = node + (size_t)i * DIMS;                  // Euclidean (curv 0)
  const float* xl = xe + (size_t)N_NODES * DIMS;              // Lorentz  (curv -1)
  const float* xs = xl + (size_t)N_NODES * DIMS;              // Sphere   (curv +1)
  const float* c  = comm + k * DIMS;

  float de = 0.f, il = 0.f, isp = 0.f;
#pragma unroll
  for (int d = 0; d < DIMS; d += 4) {
    v4f a  = *(const v4f*)(xe + d);
    v4f b  = *(const v4f*)(xl + d);
    v4f e  = *(const v4f*)(xs + d);
    v4f cv = *(const v4f*)(c + d);
    v4f df = a - cv;
    de  += df.x * df.x + df.y * df.y + df.z * df.z + df.w * df.w;
    il  += b.x * cv.x + b.y * cv.y + b.z * cv.z + b.w * cv.w;
    isp += e.x * cv.x + e.y * cv.y + e.z * cv.z + e.w * cv.w;
  }

  // Lorentz (kk = 1): lip = <x,c> - 2*x0*c0 ; d = arccosh(max(-lip, 1+eps))
  float lip = il - 2.0f * xl[0] * c[0];
  float arg = fmaxf(-lip, 1.0f + 1e-7f);
  float d1  = acoshf(arg);
  // Sphere: d = arccos(clip(<x,c>, -1+eps, 1-eps))
  float cs = fminf(fmaxf(isp, -1.0f + 1e-7f), 1.0f - 1e-7f);
  float d2 = acosf(cs);

  float dn = sqrtf(de + d1 * d1 + d2 * d2);

  // softmax over the 16 lanes sharing this node (lane mask bits 0..3)
  float m = dn;
#pragma unroll
  for (int off = 1; off < 16; off <<= 1) m = fmaxf(m, __shfl_xor(m, off));
  float ex = expf(dn - m);
  float ss = ex;
#pragma unroll
  for (int off = 1; off < 16; off <<= 1) ss += __shfl_xor(ss, off);

  pi[t] = ex / ss;   // coalesced: t = i*16 + k
}

// ---------------------------------------------------------------------------
// Kernel 2: single streaming pass over ricci.
//   acc[r][k] = sum_j ricci[i0+r, j] * pi[j, k]    (partial over this block's j)
//   intra += sum_{r,k} pi[i0+r,k] * acc[r][k]
//   inter += sum_{r,k} acc[r][k]                   (since sum_k pi[j,k] = s[j])
// 8 rows/block, 16 k-accumulators/thread (128 VGPR acc), v4f j-quads.
// ricci loads are nontemporal so the 512 KB pi table stays L2-resident.
// ---------------------------------------------------------------------------
__device__ __forceinline__ void fma4(v4f& a, float w, const v4f p) {
  a += w * p;
}

__global__ __launch_bounds__(256, 2) void k_main(
    const float* __restrict__ ricci,   // (8192, 8192)
    const float* __restrict__ pi,      // (8192, 16)
    double* __restrict__ accum)        // [0]=intra_sum, [1]=inter_sum
{
  const int rb = blockIdx.x >> 1;       // 1024 row-groups
  const int cb = blockIdx.x & 1;        // 2 column chunks
  const int i0 = rb * MROWS;
  const int j0 = cb * CBLK;
  const v4f* __restrict__ pi4 = (const v4f*)pi;

  v4f acc[MROWS][4] = {};

  for (int it = 0; it < CBLK / (4 * 256); ++it) {   // 4 iterations
    const int j = j0 + (((it << 8) + (int)threadIdx.x) << 2);

    v4f rv[MROWS];
#pragma unroll
    for (int r = 0; r < MROWS; ++r)
      rv[r] = __builtin_nontemporal_load(
          (const v4f*)(ricci + (size_t)(i0 + r) * N_NODES + j));

#pragma unroll
    for (int jj = 0; jj < 4; ++jj) {
      v4f p0 = pi4[(j + jj) * 4 + 0];
      v4f p1 = pi4[(j + jj) * 4 + 1];
      v4f p2 = pi4[(j + jj) * 4 + 2];
      v4f p3 = pi4[(j + jj) * 4 + 3];
#pragma unroll
      for (int r = 0; r < MROWS; ++r) {
        const float w = (jj == 0) ? rv[r].x : (jj == 1) ? rv[r].y
                      : (jj == 2) ? rv[r].z : rv[r].w;
        fma4(acc[r][0], w, p0);
        fma4(acc[r][1], w, p1);
        fma4(acc[r][2], w, p2);
        fma4(acc[r][3], w, p3);
      }
    }
  }

  // per-thread epilogue: fold acc with pi rows i0..i0+7 (broadcast loads)
  float fintra = 0.f, finter = 0.f;
#pragma unroll
  for (int r = 0; r < MROWS; ++r) {
#pragma unroll
    for (int q = 0; q < 4; ++q) {
      v4f pr = pi4[(i0 + r) * 4 + q];
      v4f a  = acc[r][q];
      fintra += pr.x * a.x + pr.y * a.y + pr.z * a.z + pr.w * a.w;
      finter += a.x + a.y + a.z + a.w;
    }
  }

  // wave reduce (64 lanes) in double, then block reduce, 2 atomics/block
  double di = (double)fintra, dn = (double)finter;
#pragma unroll
  for (int off = 32; off > 0; off >>= 1) {
    di += __shfl_down(di, off);
    dn += __shfl_down(dn, off);
  }
  __shared__ double red[8];
  const int w = threadIdx.x >> 6;
  if ((threadIdx.x & 63) == 0) { red[w] = di; red[4 + w] = dn; }
  __syncthreads();
  if (threadIdx.x == 0) {
    atomicAdd(&accum[0], red[0] + red[1] + red[2] + red[3]);
    atomicAdd(&accum[1], red[4] + red[5] + red[6] + red[7]);
  }
}

// ---------------------------------------------------------------------------
// Kernel 3: out = alpha * intra_sum/(K*N) - inter_sum/(K*K*N)
// ---------------------------------------------------------------------------
__global__ void k_final(const double* __restrict__ accum,
                        const float* __restrict__ alpha,
                        float* __restrict__ out)
{
  const double KN  = (double)N_COMM * (double)N_NODES;
  const double KKN = (double)N_COMM * (double)N_COMM * (double)N_NODES;
  out[0] = (float)((double)alpha[0] * (accum[0] / KN) - accum[1] / KKN);
}

extern "C" void kernel_launch(void* const* d_in, const int* in_sizes, int n_in,
                              void* d_out, int out_size, void* d_ws, size_t ws_size,
                              hipStream_t stream) {
  (void)in_sizes; (void)n_in; (void)out_size; (void)ws_size;

  const float* node  = (const float*)d_in[0];  // (3, 8192, 64) fp32
  const float* comm  = (const float*)d_in[1];  // (16, 64) fp32
  const float* ricci = (const float*)d_in[2];  // (8192, 8192) fp32
  const float* alpha = (const float*)d_in[3];  // scalar fp32
  float* out = (float*)d_out;

  double* accum = (double*)d_ws;                     // 2 doubles @ offset 0
  float*  pi    = (float*)((char*)d_ws + 64);        // 8192*16 fp32 = 512 KB

  // ws is re-poisoned to 0xAA before every launch: zero the accumulators.
  (void)hipMemsetAsync(d_ws, 0, 64, stream);

  hipLaunchKernelGGL(k_pi,   dim3((N_NODES * N_COMM) / 256), dim3(256), 0, stream,
                     node, comm, pi);
  hipLaunchKernelGGL(k_main, dim3((N_NODES / MROWS) * (N_NODES / CBLK)), dim3(256),
                     0, stream, ricci, pi, accum);
  hipLaunchKernelGGL(k_final, dim3(1), dim3(1), 0, stream, accum, alpha, out);
}

// Round 3
// 493.304 us; speedup vs baseline: 1.0137x; 1.0137x over previous
//
#include <hip/hip_runtime.h>
#include <math.h>

#define N_NODES 8192
#define N_COMM 16
#define DIMS 64
#define MROWS 8      // rows of ricci per block
#define NCHUNK 4     // column chunks (j-range 2048 per block)

typedef float v4f __attribute__((ext_vector_type(4)));

// ---------------------------------------------------------------------------
// Kernel 1: pi[i,k] = softmax_k( sqrt(d_euc^2 + d_lor^2 + d_sph^2) )
// One lane per (node, k): t = i*16 + k. 16-lane softmax via shfl_xor(1,2,4,8).
// ---------------------------------------------------------------------------
__global__ __launch_bounds__(256) void k_pi(
    const float* __restrict__ node,   // (3, 8192, 64)
    const float* __restrict__ comm,   // (16, 64)
    float* __restrict__ pi)           // (8192, 16)
{
  const int t = blockIdx.x * blockDim.x + threadIdx.x;  // 0..131071
  const int i = t >> 4;
  const int k = t & 15;

  const float* xe = node + (size_t)i * DIMS;                  // Euclidean (curv 0)
  const float* xl = xe + (size_t)N_NODES * DIMS;              // Lorentz  (curv -1)
  const float* xs = xl + (size_t)N_NODES * DIMS;              // Sphere   (curv +1)
  const float* c  = comm + k * DIMS;

  float de = 0.f, il = 0.f, isp = 0.f;
#pragma unroll
  for (int d = 0; d < DIMS; d += 4) {
    v4f a  = *(const v4f*)(xe + d);
    v4f b  = *(const v4f*)(xl + d);
    v4f e  = *(const v4f*)(xs + d);
    v4f cv = *(const v4f*)(c + d);
    v4f df = a - cv;
    de  += df.x * df.x + df.y * df.y + df.z * df.z + df.w * df.w;
    il  += b.x * cv.x + b.y * cv.y + b.z * cv.z + b.w * cv.w;
    isp += e.x * cv.x + e.y * cv.y + e.z * cv.z + e.w * cv.w;
  }

  // Lorentz (kk = 1): lip = <x,c> - 2*x0*c0 ; d = arccosh(max(-lip, 1+eps))
  float lip = il - 2.0f * xl[0] * c[0];
  float arg = fmaxf(-lip, 1.0f + 1e-7f);
  float d1  = acoshf(arg);
  // Sphere: d = arccos(clip(<x,c>, -1+eps, 1-eps))
  float cs = fminf(fmaxf(isp, -1.0f + 1e-7f), 1.0f - 1e-7f);
  float d2 = acosf(cs);

  float dn = sqrtf(de + d1 * d1 + d2 * d2);

  // softmax over the 16 lanes sharing this node (lane mask bits 0..3)
  float m = dn;
#pragma unroll
  for (int off = 1; off < 16; off <<= 1) m = fmaxf(m, __shfl_xor(m, off));
  float ex = expf(dn - m);
  float ss = ex;
#pragma unroll
  for (int off = 1; off < 16; off <<= 1) ss += __shfl_xor(ss, off);

  pi[t] = ex / ss;   // coalesced: t = i*16 + k
}

// ---------------------------------------------------------------------------
// Kernel 2: single streaming pass over ricci.
// Thread owns ONE j per iteration (lane-contiguous j):
//   - ricci loads: scalar dword, lane stride 4 B (dense 256 B / instr)
//   - pi row load: 4x dwordx4 at lane stride 64 B (dense 4 KB / wave-instr set)
//   acc[r][q] (v4f over k) += ricci[i0+r][j] * pi[j][4q..4q+3]
//   intra += sum pi[i0+r][k]*acc ; inter += sum acc   (s = pi.sum(1) absorbed)
// ---------------------------------------------------------------------------
__global__ __launch_bounds__(256) void k_main(
    const float* __restrict__ ricci,   // (8192, 8192)
    const float* __restrict__ pi,      // (8192, 16)
    double* __restrict__ accum)        // [0]=intra_sum, [1]=inter_sum
{
  const int rb = blockIdx.x >> 2;            // 1024 row-groups
  const int cb = blockIdx.x & (NCHUNK - 1);  // 4 column chunks
  const int i0 = rb * MROWS;
  const int j0 = cb * (N_NODES / NCHUNK);
  const int tid = threadIdx.x;
  const v4f* __restrict__ pi4 = (const v4f*)pi;

  v4f acc[MROWS][4] = {};

  for (int it = 0; it < (N_NODES / NCHUNK) / 256; ++it) {   // 8 iterations
    const int j = j0 + (it << 8) + tid;

    // pi row j: dense per-wave 4 KB window
    v4f p0 = pi4[j * 4 + 0];
    v4f p1 = pi4[j * 4 + 1];
    v4f p2 = pi4[j * 4 + 2];
    v4f p3 = pi4[j * 4 + 3];

    // 8 ricci values for column j: perfectly coalesced scalar loads
    float rv[MROWS];
#pragma unroll
    for (int r = 0; r < MROWS; ++r)
      rv[r] = ricci[(size_t)(i0 + r) * N_NODES + j];

#pragma unroll
    for (int r = 0; r < MROWS; ++r) {
      acc[r][0] += rv[r] * p0;
      acc[r][1] += rv[r] * p1;
      acc[r][2] += rv[r] * p2;
      acc[r][3] += rv[r] * p3;
    }
  }

  // per-thread epilogue: fold acc with pi rows i0..i0+7 (broadcast loads)
  float fintra = 0.f, finter = 0.f;
#pragma unroll
  for (int r = 0; r < MROWS; ++r) {
#pragma unroll
    for (int q = 0; q < 4; ++q) {
      v4f pr = pi4[(i0 + r) * 4 + q];
      v4f a  = acc[r][q];
      fintra += pr.x * a.x + pr.y * a.y + pr.z * a.z + pr.w * a.w;
      finter += a.x + a.y + a.z + a.w;
    }
  }

  // wave reduce (64 lanes) in double, then block reduce, 2 atomics/block
  double di = (double)fintra, dn = (double)finter;
#pragma unroll
  for (int off = 32; off > 0; off >>= 1) {
    di += __shfl_down(di, off);
    dn += __shfl_down(dn, off);
  }
  __shared__ double red[8];
  const int w = tid >> 6;
  if ((tid & 63) == 0) { red[w] = di; red[4 + w] = dn; }
  __syncthreads();
  if (tid == 0) {
    atomicAdd(&accum[0], red[0] + red[1] + red[2] + red[3]);
    atomicAdd(&accum[1], red[4] + red[5] + red[6] + red[7]);
  }
}

// ---------------------------------------------------------------------------
// Kernel 3: out = alpha * intra_sum/(K*N) - inter_sum/(K*K*N)
// ---------------------------------------------------------------------------
__global__ void k_final(const double* __restrict__ accum,
                        const float* __restrict__ alpha,
                        float* __restrict__ out)
{
  const double KN  = (double)N_COMM * (double)N_NODES;
  const double KKN = (double)N_COMM * (double)N_COMM * (double)N_NODES;
  out[0] = (float)((double)alpha[0] * (accum[0] / KN) - accum[1] / KKN);
}

extern "C" void kernel_launch(void* const* d_in, const int* in_sizes, int n_in,
                              void* d_out, int out_size, void* d_ws, size_t ws_size,
                              hipStream_t stream) {
  (void)in_sizes; (void)n_in; (void)out_size; (void)ws_size;

  const float* node  = (const float*)d_in[0];  // (3, 8192, 64) fp32
  const float* comm  = (const float*)d_in[1];  // (16, 64) fp32
  const float* ricci = (const float*)d_in[2];  // (8192, 8192) fp32
  const float* alpha = (const float*)d_in[3];  // scalar fp32
  float* out = (float*)d_out;

  double* accum = (double*)d_ws;                     // 2 doubles @ offset 0
  float*  pi    = (float*)((char*)d_ws + 64);        // 8192*16 fp32 = 512 KB

  // ws is re-poisoned to 0xAA before every launch: zero the accumulators.
  (void)hipMemsetAsync(d_ws, 0, 64, stream);

  hipLaunchKernelGGL(k_pi,   dim3((N_NODES * N_COMM) / 256), dim3(256), 0, stream,
                     node, comm, pi);
  hipLaunchKernelGGL(k_main, dim3((N_NODES / MROWS) * NCHUNK), dim3(256),
                     0, stream, ricci, pi, accum);
  hipLaunchKernelGGL(k_final, dim3(1), dim3(1), 0, stream, accum, alpha, out);
}